// Round 16
// baseline (795.614 us; speedup 1.0000x reference)
//
#include <hip/hip_runtime.h>
#include <hip/hip_cooperative_groups.h>
#include <math.h>

namespace cg = cooperative_groups;

#define NN 50000
#define NE 640000
#define CAP 64   // fixed neighbor-slot capacity; Poisson(12.8) max deg ~40 << 64

typedef short short8 __attribute__((ext_vector_type(8)));   // 8 bf16 (4 VGPRs)
typedef float f32x4  __attribute__((ext_vector_type(4)));   // MFMA accumulator

// ---- bf16 helpers (RNE pack, cheap unpack) ----------------------------------
__device__ __forceinline__ unsigned bfr(float f) {
    unsigned u = __float_as_uint(f);
    return (u + 0x7FFFu + ((u >> 16) & 1u)) >> 16;
}
__device__ __forceinline__ unsigned pk2(float a, float b) { return bfr(a) | (bfr(b) << 16); }
__device__ __forceinline__ float bflo(unsigned u) { return __uint_as_float(u << 16); }
__device__ __forceinline__ float bfhi(unsigned u) { return __uint_as_float(u & 0xFFFF0000u); }

// ---- weight pack into MFMA B-frag layout (bf16) -----------------------------
__device__ __forceinline__ void packOne(const float* Wl, const float* Wr,
                                        unsigned short* wp, int idx,
                                        int CIN, int COUT) {
    int k = idx / COUT, n = idx % COUT;
    float v = (k < CIN) ? Wl[k * COUT + n] : Wr[(k - CIN) * COUT + n];
    int kt = k >> 5, quad = (k >> 3) & 3, j = k & 7;
    int nt = n >> 4, l16 = n & 15;
    int NT = COUT / 16;
    wp[(((kt * NT + nt) * 64) + quad * 16 + l16) * 8 + j] = (unsigned short)bfr(v);
}

// ---- gather-aggregate phase (R11-verified inner loop), wave-grid-strided ----
template <int LOGC>
__device__ __forceinline__ void
agg_phase(const unsigned* __restrict__ xu, const int* __restrict__ nbr,
          const int* __restrict__ cnt, unsigned* __restrict__ aggu,
          int wgl, int nwave, int lane) {
    constexpr int RU = 1 << (LOGC - 1);   // uints/row: 32 (C=64) | 64 (C=128)
    constexpr int PC = RU / 16;           // uints per lane16: 2 | 4
    const int qw = lane >> 4, l16 = lane & 15;

    for (int gw = wgl; gw < NN; gw += nwave) {
        const int deg = cnt[gw];
        const int m = (deg < CAP) ? deg : CAP;

        int idx = 0;
        if (lane < m) idx = nbr[gw * CAP + lane];

        float a[2 * PC] = {};

#pragma unroll 4
        for (int j = 0; j < m; j += 4) {
            const int n = __shfl(idx, (j + qw) & 63);
            const bool valid = (j + qw) < m;
            if (PC == 2) {
                const uint2 u = *(const uint2*)(xu + (size_t)n * RU + l16 * 2);
                if (valid) {
                    a[0] += bflo(u.x); a[1] += bfhi(u.x);
                    a[2] += bflo(u.y); a[3] += bfhi(u.y);
                }
            } else {
                const uint4 u = *(const uint4*)(xu + (size_t)n * RU + l16 * 4);
                if (valid) {
                    a[0] += bflo(u.x); a[1] += bfhi(u.x);
                    a[2] += bflo(u.y); a[3] += bfhi(u.y);
                    a[4] += bflo(u.z); a[5] += bfhi(u.z);
                    a[6] += bflo(u.w); a[7] += bfhi(u.w);
                }
            }
        }

#pragma unroll
        for (int c = 0; c < 2 * PC; ++c) {
            a[c] += __shfl_xor(a[c], 16);
            a[c] += __shfl_xor(a[c], 32);
        }

        if (qw == 0) {
            const float di = 1.0f / (float)((deg > 1) ? deg : 1);
            if (PC == 2) {
                uint2 o = make_uint2(pk2(a[0] * di, a[1] * di), pk2(a[2] * di, a[3] * di));
                *(uint2*)(aggu + (size_t)gw * RU + l16 * 2) = o;
            } else {
                uint4 o = make_uint4(pk2(a[0] * di, a[1] * di), pk2(a[2] * di, a[3] * di),
                                     pk2(a[4] * di, a[5] * di), pk2(a[6] * di, a[7] * di));
                *(uint4*)(aggu + (size_t)gw * RU + l16 * 4) = o;
            }
        }
    }
}

// ---- MFMA GEMM phase: ONE 16-row strip per wave (low VGPR) ------------------
template <int CIN, int COUT, bool RELU>
__device__ __forceinline__ void
mfma_phase(const unsigned short* __restrict__ Agg, const unsigned short* __restrict__ X,
           const unsigned short* __restrict__ Wpack, const float* __restrict__ bias,
           unsigned short* __restrict__ outp, int blk, int gstride, int wave, int lane) {
    constexpr int KT = (2 * CIN) / 32;
    constexpr int NT = COUT / 16;
    const int quad = lane >> 4, l16 = lane & 15;
    const int NTILE = (NN + 63) / 64;

    for (int tile = blk; tile < NTILE; tile += gstride) {
        const int row_base = tile * 64 + wave * 16;
        int r0 = row_base + l16; if (r0 >= NN) r0 = NN - 1;

        f32x4 acc[NT] = {};

        for (int kt = 0; kt < KT; ++kt) {
            const unsigned short* P = (kt < KT / 2) ? Agg : X;
            const int kb = (kt < KT / 2) ? kt * 32 : kt * 32 - CIN;
            const short8 a0 = *(const short8*)(P + (size_t)r0 * CIN + kb + quad * 8);
#pragma unroll
            for (int nt = 0; nt < NT; ++nt) {
                const short8 bfrag = *(const short8*)(Wpack + (size_t)((kt * NT + nt) * 64 + lane) * 8);
                acc[nt] = __builtin_amdgcn_mfma_f32_16x16x32_bf16(a0, bfrag, acc[nt], 0, 0, 0);
            }
        }

#pragma unroll
        for (int nt = 0; nt < NT; ++nt) {
            const int col = nt * 16 + l16;
            const float bb = bias[col];
#pragma unroll
            for (int rg = 0; rg < 4; ++rg) {
                int row = row_base + quad * 4 + rg;
                if (row < NN) {
                    float v = acc[nt][rg] + bb;
                    if (RELU) v = fmaxf(v, 0.f);
                    outp[(size_t)row * COUT + col] = (unsigned short)bfr(v);
                }
            }
        }
    }
}

// ---- layer-2 GEMM + fused classifier, ONE strip per wave --------------------
__device__ __forceinline__ void
cls_phase(const unsigned short* __restrict__ Agg, const unsigned short* __restrict__ X,
          const unsigned short* __restrict__ Wpack, const unsigned short* __restrict__ WpackC,
          const float* __restrict__ bias, const float* __restrict__ bc1,
          const float* __restrict__ Wc2, const float* __restrict__ bc2,
          float* __restrict__ out, short* __restrict__ Hs,
          int blk, int gstride, int wave, int lane) {
    constexpr int CIN = 128, NT = 4, KT = 8;
    const int quad = lane >> 4, l16 = lane & 15;
    const int NTILE = (NN + 63) / 64;

    for (int tile = blk; tile < NTILE; tile += gstride) {
        const int row_base = tile * 64 + wave * 16;
        int r0 = row_base + l16; if (r0 >= NN) r0 = NN - 1;

        f32x4 acc[NT] = {};

        for (int kt = 0; kt < KT; ++kt) {
            const unsigned short* P = (kt < KT / 2) ? Agg : X;
            const int kb = (kt < KT / 2) ? kt * 32 : kt * 32 - CIN;
            const short8 a0 = *(const short8*)(P + (size_t)r0 * CIN + kb + quad * 8);
#pragma unroll
            for (int nt = 0; nt < NT; ++nt) {
                const short8 bfrag = *(const short8*)(Wpack + (size_t)((kt * NT + nt) * 64 + lane) * 8);
                acc[nt] = __builtin_amdgcn_mfma_f32_16x16x32_bf16(a0, bfrag, acc[nt], 0, 0, 0);
            }
        }

        short* hw = Hs + wave * 1024;   // 16 rows x 64 cols
#pragma unroll
        for (int nt = 0; nt < NT; ++nt) {
            const float bb = bias[nt * 16 + l16];
#pragma unroll
            for (int rg = 0; rg < 4; ++rg)
                hw[(quad * 4 + rg) * 64 + nt * 16 + l16] =
                    (unsigned short)bfr(acc[nt][rg] + bb);
        }
        __syncthreads();

        f32x4 sacc[2] = {};
#pragma unroll
        for (int kt2 = 0; kt2 < 2; ++kt2) {
            const short8 af = *(const short8*)&hw[l16 * 64 + kt2 * 32 + quad * 8];
#pragma unroll
            for (int nt2 = 0; nt2 < 2; ++nt2) {
                const short8 bf = *(const short8*)(WpackC + (size_t)((kt2 * 2 + nt2) * 64 + lane) * 8);
                sacc[nt2] = __builtin_amdgcn_mfma_f32_16x16x32_bf16(af, bf, sacc[nt2], 0, 0, 0);
            }
        }

        const float b1a = bc1[l16], b1b = bc1[16 + l16];
        const float w2a = Wc2[l16], w2b = Wc2[16 + l16];
        const float b2v = bc2[0];
#pragma unroll
        for (int rg = 0; rg < 4; ++rg) {
            float p = fmaxf(sacc[0][rg] + b1a, 0.f) * w2a +
                      fmaxf(sacc[1][rg] + b1b, 0.f) * w2b;
#pragma unroll
            for (int off = 1; off < 16; off <<= 1) p += __shfl_xor(p, off);
            if (l16 == 0) {
                int row = row_base + quad * 4 + rg;
                if (row < NN) out[row] = 1.0f / (1.0f + expf(-(p + b2v)));
            }
        }
        __syncthreads();
    }
}

// ---- ONE cooperative kernel (grid-size agnostic, VGPR-capped) ---------------
__global__ __launch_bounds__(256, 4) void
k_all(const int* __restrict__ src, const int* __restrict__ dst,
      const float* __restrict__ x,
      const float* Wl0, const float* Wr0, const float* b0,
      const float* Wl1, const float* Wr1, const float* b1,
      const float* Wl2, const float* Wr2, const float* b2,
      const float* Wc1, const float* bc1, const float* Wc2, const float* bc2,
      int* cnt, int* nbr, unsigned short* xb,
      unsigned short* wp0, unsigned short* wp1, unsigned short* wp2,
      unsigned short* wpc,
      unsigned short* aggb, unsigned short* h0b, unsigned short* h1b,
      float* out) {
    cg::grid_group grid = cg::this_grid();

    __shared__ __align__(16) short Hs[4 * 16 * 64];   // 8 KB (classifier phase)

    const int t = threadIdx.x, b = blockIdx.x;
    const int nthr = gridDim.x * 256;
    const int nwave = nthr >> 6;
    const int gt = b * 256 + t;
    const int wave = t >> 6, lane = t & 63;
    const int wgl = gt >> 6;

    // ---- phase 1: bucket-CSR fill + x->bf16 + weight packs (cnt pre-zeroed) --
    for (int e = gt; e < NE; e += nthr) {
        int d = dst[e];
        int p = atomicAdd(&cnt[d], 1);
        if (p < CAP) nbr[d * CAP + p] = src[e];
    }
    for (int i = gt; i < NN * 16; i += nthr) {
        float4 v = ((const float4*)x)[i];
        ((uint2*)xb)[i] = make_uint2(pk2(v.x, v.y), pk2(v.z, v.w));
    }
    for (int i = gt; i < 67584; i += nthr) {
        if (i < 16384) packOne(Wl0, Wr0, wp0, i, 64, 128);
        else if (i < 49152) packOne(Wl1, Wr1, wp1, i - 16384, 128, 128);
        else if (i < 65536) packOne(Wl2, Wr2, wp2, i - 49152, 128, 64);
        else packOne(Wc1, Wc1, wpc, i - 65536, 64, 32);
    }
    grid.sync();

    // ---- layer 0 ----
    agg_phase<6>((const unsigned*)xb, nbr, cnt, (unsigned*)aggb, wgl, nwave, lane);
    grid.sync();
    mfma_phase<64, 128, true>(aggb, xb, wp0, b0, h0b, b, gridDim.x, wave, lane);
    grid.sync();

    // ---- layer 1 ----
    agg_phase<7>((const unsigned*)h0b, nbr, cnt, (unsigned*)aggb, wgl, nwave, lane);
    grid.sync();
    mfma_phase<128, 128, true>(aggb, h0b, wp1, b1, h1b, b, gridDim.x, wave, lane);
    grid.sync();

    // ---- layer 2 ----
    agg_phase<7>((const unsigned*)h1b, nbr, cnt, (unsigned*)aggb, wgl, nwave, lane);
    grid.sync();
    cls_phase(aggb, h1b, wp2, wpc, b2, bc1, Wc2, bc2, out, Hs, b, gridDim.x, wave, lane);
}

// ================= fallback kernels (R11 structure, new tiles) ===============
__global__ __launch_bounds__(256) void
k_prep(const int* __restrict__ src, const int* __restrict__ dst,
       int* __restrict__ cnt, int* __restrict__ nbr,
       const float* __restrict__ x, unsigned* __restrict__ xb,
       const float* Wl0, const float* Wr0, const float* Wl1, const float* Wr1,
       const float* Wl2, const float* Wr2, const float* Wc1,
       unsigned short* wp0, unsigned short* wp1, unsigned short* wp2,
       unsigned short* wpc) {
    const int b = blockIdx.x, t = threadIdx.x;
    if (b < 2500) {
        int e = b * 256 + t;
        if (e < NE) {
            int d = dst[e];
            int p = atomicAdd(&cnt[d], 1);
            if (p < CAP) nbr[d * CAP + p] = src[e];
        }
    } else if (b < 5625) {
        int i = (b - 2500) * 256 + t;
        if (i < NN * 16) {
            float4 v = ((const float4*)x)[i];
            ((uint2*)xb)[i] = make_uint2(pk2(v.x, v.y), pk2(v.z, v.w));
        }
    } else {
        int idx = (b - 5625) * 256 + t;
        if (idx < 16384) packOne(Wl0, Wr0, wp0, idx, 64, 128);
        else if (idx < 49152) packOne(Wl1, Wr1, wp1, idx - 16384, 128, 128);
        else if (idx < 65536) packOne(Wl2, Wr2, wp2, idx - 49152, 128, 64);
        else if (idx < 67584) packOne(Wc1, Wc1, wpc, idx - 65536, 64, 32);
    }
}

template <int LOGC>
__global__ __launch_bounds__(256) void
k_aggregate(const unsigned* __restrict__ xu, const int* __restrict__ nbr,
            const int* __restrict__ cnt, unsigned* __restrict__ aggu, int N) {
    const int wgl = (blockIdx.x * 256 + threadIdx.x) >> 6;
    if (wgl >= N) return;
    agg_phase<LOGC>(xu, nbr, cnt, aggu, wgl, 1 << 30, threadIdx.x & 63);
}

template <int CIN, int COUT, bool RELU>
__global__ __launch_bounds__(256) void
k_mfma(const unsigned short* __restrict__ Agg, const unsigned short* __restrict__ X,
       const unsigned short* __restrict__ Wpack, const float* __restrict__ bias,
       unsigned short* __restrict__ outp, int N) {
    mfma_phase<CIN, COUT, RELU>(Agg, X, Wpack, bias, outp,
                                blockIdx.x, 1 << 30, threadIdx.x >> 6, threadIdx.x & 63);
}

__global__ __launch_bounds__(256) void
k_mfma_cls(const unsigned short* __restrict__ Agg, const unsigned short* __restrict__ X,
           const unsigned short* __restrict__ Wpack, const unsigned short* __restrict__ WpackC,
           const float* __restrict__ bias, const float* __restrict__ bc1,
           const float* __restrict__ Wc2, const float* __restrict__ bc2,
           float* __restrict__ out, int N) {
    __shared__ __align__(16) short Hs[4 * 16 * 64];
    cls_phase(Agg, X, Wpack, WpackC, bias, bc1, Wc2, bc2, out, Hs,
              blockIdx.x, 1 << 30, threadIdx.x >> 6, threadIdx.x & 63);
}

extern "C" void kernel_launch(void* const* d_in, const int* in_sizes, int n_in,
                              void* d_out, int out_size, void* d_ws, size_t ws_size,
                              hipStream_t stream) {
    const float* x   = (const float*)d_in[0];
    const int*   ei  = (const int*)d_in[1];   // [2, NE] int32
    const int*   src = ei;
    const int*   dst = ei + NE;
    const float* Wl0 = (const float*)d_in[2];
    const float* Wr0 = (const float*)d_in[3];
    const float* b0  = (const float*)d_in[4];
    const float* Wl1 = (const float*)d_in[5];
    const float* Wr1 = (const float*)d_in[6];
    const float* b1  = (const float*)d_in[7];
    const float* Wl2 = (const float*)d_in[8];
    const float* Wr2 = (const float*)d_in[9];
    const float* b2  = (const float*)d_in[10];
    const float* Wc1 = (const float*)d_in[11];
    const float* bc1 = (const float*)d_in[12];
    const float* Wc2 = (const float*)d_in[13];
    const float* bc2 = (const float*)d_in[14];
    float* out = (float*)d_out;

    char*  ws   = (char*)d_ws;
    int*   cnt  = (int*)(ws);
    unsigned short* wp0 = (unsigned short*)(ws + (size_t)256 * 1024);
    unsigned short* wp1 = (unsigned short*)(ws + (size_t)352 * 1024);
    unsigned short* wp2 = (unsigned short*)(ws + (size_t)448 * 1024);
    unsigned short* wpc = (unsigned short*)(ws + (size_t)512 * 1024);
    int*   nbr  = (int*)(ws + (size_t)1 * (1 << 20));
    unsigned short* xb   = (unsigned short*)(ws + (size_t)16 * (1 << 20));
    unsigned short* aggb = (unsigned short*)(ws + (size_t)24 * (1 << 20));
    unsigned short* h0b  = (unsigned short*)(ws + (size_t)40 * (1 << 20));
    unsigned short* h1b  = (unsigned short*)(ws + (size_t)56 * (1 << 20));

    hipMemsetAsync(cnt, 0, (size_t)NN * sizeof(int), stream);

    // ---- cooperative single-kernel path ----
    // Grid clamped to 4 blocks/CU (1024): R15 showed grid.sync cost explodes at
    // 2048 blocks (spin-poll FETCH + idle pipes); R14 showed 512 is cheap.
    bool coop_ok = false;
    int maxBpc = 0, ncu = 0, dev = 0;
    hipGetDevice(&dev);
    hipDeviceGetAttribute(&ncu, hipDeviceAttributeMultiprocessorCount, dev);
    hipError_t qerr = hipOccupancyMaxActiveBlocksPerMultiprocessor(
        &maxBpc, (const void*)k_all, 256, 0);
    if (qerr == hipSuccess && maxBpc > 0 && ncu > 0) {
        int bpc = (maxBpc < 4) ? maxBpc : 4;
        int grid = bpc * ncu;
        if (grid > 1024) grid = 1024;
        const int* srcp = src; const int* dstp = dst;
        void* args[] = {
            (void*)&srcp, (void*)&dstp, (void*)&x,
            (void*)&Wl0, (void*)&Wr0, (void*)&b0,
            (void*)&Wl1, (void*)&Wr1, (void*)&b1,
            (void*)&Wl2, (void*)&Wr2, (void*)&b2,
            (void*)&Wc1, (void*)&bc1, (void*)&Wc2, (void*)&bc2,
            (void*)&cnt, (void*)&nbr, (void*)&xb,
            (void*)&wp0, (void*)&wp1, (void*)&wp2, (void*)&wpc,
            (void*)&aggb, (void*)&h0b, (void*)&h1b,
            (void*)&out
        };
        hipError_t lerr = hipLaunchCooperativeKernel((const void*)k_all, dim3(grid),
                                                     dim3(256), args, 0, stream);
        if (lerr == hipSuccess) coop_ok = true;
        else (void)hipGetLastError();
    } else {
        (void)hipGetLastError();
    }

    // ---- fallback: proven multi-kernel pipeline ----
    if (!coop_ok) {
        const int B = 256;
        const int AGG_GRID = (NN + 3) / 4;
        const int MFMA_GRID = (NN + 63) / 64;

        k_prep<<<5889, B, 0, stream>>>(src, dst, cnt, nbr, x, (unsigned*)xb,
                                       Wl0, Wr0, Wl1, Wr1, Wl2, Wr2, Wc1,
                                       wp0, wp1, wp2, wpc);

        k_aggregate<6><<<AGG_GRID, B, 0, stream>>>((const unsigned*)xb, nbr, cnt,
                                                   (unsigned*)aggb, NN);
        k_mfma<64, 128, true><<<MFMA_GRID, B, 0, stream>>>(aggb, xb, wp0, b0, h0b, NN);

        k_aggregate<7><<<AGG_GRID, B, 0, stream>>>((const unsigned*)h0b, nbr, cnt,
                                                   (unsigned*)aggb, NN);
        k_mfma<128, 128, true><<<MFMA_GRID, B, 0, stream>>>(aggb, h0b, wp1, b1, h1b, NN);

        k_aggregate<7><<<AGG_GRID, B, 0, stream>>>((const unsigned*)h1b, nbr, cnt,
                                                   (unsigned*)aggb, NN);
        k_mfma_cls<<<MFMA_GRID, B, 0, stream>>>(aggb, h1b, wp2, wpc, b2, bc1, Wc2, bc2,
                                                out, NN);
    }
}

// Round 17
// 625.983 us; speedup vs baseline: 1.2710x; 1.2710x over previous
//
#include <hip/hip_runtime.h>
#include <hip/hip_cooperative_groups.h>
#include <math.h>

namespace cg = cooperative_groups;

#define NN 50000
#define NE 640000
#define CAP 64   // fixed neighbor-slot capacity; Poisson(12.8) max deg ~40 << 64
#define NSTRIP ((NN + 15) / 16)   // 3125 16-row strips

typedef short short8 __attribute__((ext_vector_type(8)));   // 8 bf16 (4 VGPRs)
typedef float f32x4  __attribute__((ext_vector_type(4)));   // MFMA accumulator

// ---- bf16 helpers (RNE pack, cheap unpack) ----------------------------------
__device__ __forceinline__ unsigned bfr(float f) {
    unsigned u = __float_as_uint(f);
    return (u + 0x7FFFu + ((u >> 16) & 1u)) >> 16;
}
__device__ __forceinline__ unsigned pk2(float a, float b) { return bfr(a) | (bfr(b) << 16); }
__device__ __forceinline__ float bflo(unsigned u) { return __uint_as_float(u << 16); }
__device__ __forceinline__ float bfhi(unsigned u) { return __uint_as_float(u & 0xFFFF0000u); }

// ---- weight pack into MFMA B-frag layout (bf16) -----------------------------
__device__ __forceinline__ void packOne(const float* Wl, const float* Wr,
                                        unsigned short* wp, int idx,
                                        int CIN, int COUT) {
    int k = idx / COUT, n = idx % COUT;
    float v = (k < CIN) ? Wl[k * COUT + n] : Wr[(k - CIN) * COUT + n];
    int kt = k >> 5, quad = (k >> 3) & 3, j = k & 7;
    int nt = n >> 4, l16 = n & 15;
    int NT = COUT / 16;
    wp[(((kt * NT + nt) * 64) + quad * 16 + l16) * 8 + j] = (unsigned short)bfr(v);
}

// ---- gather-aggregate (R11-verified inner loop), wave-strided over nodes ----
template <int LOGC>
__device__ __forceinline__ void
agg_phase(const unsigned* __restrict__ xu, const int* __restrict__ nbr,
          const int* __restrict__ cnt, unsigned* __restrict__ aggu,
          int wgl, int nwave, int lane) {
    constexpr int RU = 1 << (LOGC - 1);   // uints/row: 32 (C=64) | 64 (C=128)
    constexpr int PC = RU / 16;           // uints per lane16: 2 | 4
    const int qw = lane >> 4, l16 = lane & 15;

    for (int gw = wgl; gw < NN; gw += nwave) {
        const int deg = cnt[gw];
        const int m = (deg < CAP) ? deg : CAP;

        int idx = 0;
        if (lane < m) idx = nbr[gw * CAP + lane];

        float a[2 * PC] = {};

#pragma unroll 4
        for (int j = 0; j < m; j += 4) {
            const int n = __shfl(idx, (j + qw) & 63);
            const bool valid = (j + qw) < m;
            if (PC == 2) {
                const uint2 u = *(const uint2*)(xu + (size_t)n * RU + l16 * 2);
                if (valid) {
                    a[0] += bflo(u.x); a[1] += bfhi(u.x);
                    a[2] += bflo(u.y); a[3] += bfhi(u.y);
                }
            } else {
                const uint4 u = *(const uint4*)(xu + (size_t)n * RU + l16 * 4);
                if (valid) {
                    a[0] += bflo(u.x); a[1] += bfhi(u.x);
                    a[2] += bflo(u.y); a[3] += bfhi(u.y);
                    a[4] += bflo(u.z); a[5] += bfhi(u.z);
                    a[6] += bflo(u.w); a[7] += bfhi(u.w);
                }
            }
        }

#pragma unroll
        for (int c = 0; c < 2 * PC; ++c) {
            a[c] += __shfl_xor(a[c], 16);
            a[c] += __shfl_xor(a[c], 32);
        }

        if (qw == 0) {
            const float di = 1.0f / (float)((deg > 1) ? deg : 1);
            if (PC == 2) {
                uint2 o = make_uint2(pk2(a[0] * di, a[1] * di), pk2(a[2] * di, a[3] * di));
                *(uint2*)(aggu + (size_t)gw * RU + l16 * 2) = o;
            } else {
                uint4 o = make_uint4(pk2(a[0] * di, a[1] * di), pk2(a[2] * di, a[3] * di),
                                     pk2(a[4] * di, a[5] * di), pk2(a[6] * di, a[7] * di));
                *(uint4*)(aggu + (size_t)gw * RU + l16 * 4) = o;
            }
        }
    }
}

// ---- MFMA GEMM: wave-strided over 16-row strips (low VGPR) ------------------
template <int CIN, int COUT, bool RELU>
__device__ __forceinline__ void
mfma_strips(const unsigned short* __restrict__ Agg, const unsigned short* __restrict__ X,
            const unsigned short* __restrict__ Wpack, const float* __restrict__ bias,
            unsigned short* __restrict__ outp, int wstrip, int nstride, int lane) {
    constexpr int KT = (2 * CIN) / 32;
    constexpr int NT = COUT / 16;
    const int quad = lane >> 4, l16 = lane & 15;

    for (int s = wstrip; s < NSTRIP; s += nstride) {
        const int row_base = s * 16;
        int r0 = row_base + l16; if (r0 >= NN) r0 = NN - 1;

        f32x4 acc[NT] = {};

        for (int kt = 0; kt < KT; ++kt) {
            const unsigned short* P = (kt < KT / 2) ? Agg : X;
            const int kb = (kt < KT / 2) ? kt * 32 : kt * 32 - CIN;
            const short8 a0 = *(const short8*)(P + (size_t)r0 * CIN + kb + quad * 8);
#pragma unroll
            for (int nt = 0; nt < NT; ++nt) {
                const short8 bfrag = *(const short8*)(Wpack + (size_t)((kt * NT + nt) * 64 + lane) * 8);
                acc[nt] = __builtin_amdgcn_mfma_f32_16x16x32_bf16(a0, bfrag, acc[nt], 0, 0, 0);
            }
        }

#pragma unroll
        for (int nt = 0; nt < NT; ++nt) {
            const int col = nt * 16 + l16;
            const float bb = bias[col];
#pragma unroll
            for (int rg = 0; rg < 4; ++rg) {
                int row = row_base + quad * 4 + rg;
                if (row < NN) {
                    float v = acc[nt][rg] + bb;
                    if (RELU) v = fmaxf(v, 0.f);
                    outp[(size_t)row * COUT + col] = (unsigned short)bfr(v);
                }
            }
        }
    }
}

// ---- layer-2 GEMM + fused classifier, wave-strided strips, per-wave LDS -----
// No __syncthreads: hw (1 KB) is private to the wave; LDS is in-order per wave.
__device__ __forceinline__ void
cls_strips(const unsigned short* __restrict__ Agg, const unsigned short* __restrict__ X,
           const unsigned short* __restrict__ Wpack, const unsigned short* __restrict__ WpackC,
           const float* __restrict__ bias, const float* __restrict__ bc1,
           const float* __restrict__ Wc2, const float* __restrict__ bc2,
           float* __restrict__ out, short* __restrict__ hw,
           int wstrip, int nstride, int lane) {
    constexpr int CIN = 128, NT = 4, KT = 8;
    const int quad = lane >> 4, l16 = lane & 15;

    for (int s = wstrip; s < NSTRIP; s += nstride) {
        const int row_base = s * 16;
        int r0 = row_base + l16; if (r0 >= NN) r0 = NN - 1;

        f32x4 acc[NT] = {};

        for (int kt = 0; kt < KT; ++kt) {
            const unsigned short* P = (kt < KT / 2) ? Agg : X;
            const int kb = (kt < KT / 2) ? kt * 32 : kt * 32 - CIN;
            const short8 a0 = *(const short8*)(P + (size_t)r0 * CIN + kb + quad * 8);
#pragma unroll
            for (int nt = 0; nt < NT; ++nt) {
                const short8 bfrag = *(const short8*)(Wpack + (size_t)((kt * NT + nt) * 64 + lane) * 8);
                acc[nt] = __builtin_amdgcn_mfma_f32_16x16x32_bf16(a0, bfrag, acc[nt], 0, 0, 0);
            }
        }

        // h strip (C-layout) -> per-wave LDS (row-major): +b2, no relu
#pragma unroll
        for (int nt = 0; nt < NT; ++nt) {
            const float bb = bias[nt * 16 + l16];
#pragma unroll
            for (int rg = 0; rg < 4; ++rg)
                hw[(quad * 4 + rg) * 64 + nt * 16 + l16] =
                    (unsigned short)bfr(acc[nt][rg] + bb);
        }

        // classifier GEMM: h(16x64) @ Wc1(64x32); A-frag: m=l16, k=quad*8+j
        f32x4 sacc[2] = {};
#pragma unroll
        for (int kt2 = 0; kt2 < 2; ++kt2) {
            const short8 af = *(const short8*)&hw[l16 * 64 + kt2 * 32 + quad * 8];
#pragma unroll
            for (int nt2 = 0; nt2 < 2; ++nt2) {
                const short8 bf = *(const short8*)(WpackC + (size_t)((kt2 * 2 + nt2) * 64 + lane) * 8);
                sacc[nt2] = __builtin_amdgcn_mfma_f32_16x16x32_bf16(af, bf, sacc[nt2], 0, 0, 0);
            }
        }

        const float b1a = bc1[l16], b1b = bc1[16 + l16];
        const float w2a = Wc2[l16], w2b = Wc2[16 + l16];
        const float b2v = bc2[0];
#pragma unroll
        for (int rg = 0; rg < 4; ++rg) {
            float p = fmaxf(sacc[0][rg] + b1a, 0.f) * w2a +
                      fmaxf(sacc[1][rg] + b1b, 0.f) * w2b;
#pragma unroll
            for (int off = 1; off < 16; off <<= 1) p += __shfl_xor(p, off);
            if (l16 == 0) {
                int row = row_base + quad * 4 + rg;
                if (row < NN) out[row] = 1.0f / (1.0f + expf(-(p + b2v)));
            }
        }
    }
}

// ---- ONE cooperative kernel: 512-thread blocks, grid <= 512 -----------------
// R14/R15/R16 lesson: grid.sync cost explodes when blocks sit IDLE in a phase
// (spin-poll on HBM flag). 512 blocks <= every phase's work count; 8 waves/blk
// doubles gather wave-parallelism vs R14 at the same (proven-cheap) block count.
__global__ __launch_bounds__(512, 4) void
k_all(const int* __restrict__ src, const int* __restrict__ dst,
      const float* __restrict__ x,
      const float* Wl0, const float* Wr0, const float* b0,
      const float* Wl1, const float* Wr1, const float* b1,
      const float* Wl2, const float* Wr2, const float* b2,
      const float* Wc1, const float* bc1, const float* Wc2, const float* bc2,
      int* cnt, int* nbr, unsigned short* xb,
      unsigned short* wp0, unsigned short* wp1, unsigned short* wp2,
      unsigned short* wpc,
      unsigned short* aggb, unsigned short* h0b, unsigned short* h1b,
      float* out) {
    cg::grid_group grid = cg::this_grid();

    __shared__ __align__(16) short Hs[8 * 16 * 64];   // 16 KB: 1 KB per wave

    const int t = threadIdx.x, b = blockIdx.x;
    const int nthr = gridDim.x * 512;
    const int nwave = nthr >> 6;
    const int gt = b * 512 + t;
    const int wave = t >> 6, lane = t & 63;
    const int wgl = gt >> 6;

    // ---- phase 1: bucket-CSR fill + x->bf16 + weight packs (cnt pre-zeroed) --
    for (int e = gt; e < NE; e += nthr) {
        int d = dst[e];
        int p = atomicAdd(&cnt[d], 1);
        if (p < CAP) nbr[d * CAP + p] = src[e];
    }
    for (int i = gt; i < NN * 16; i += nthr) {
        float4 v = ((const float4*)x)[i];
        ((uint2*)xb)[i] = make_uint2(pk2(v.x, v.y), pk2(v.z, v.w));
    }
    for (int i = gt; i < 67584; i += nthr) {
        if (i < 16384) packOne(Wl0, Wr0, wp0, i, 64, 128);
        else if (i < 49152) packOne(Wl1, Wr1, wp1, i - 16384, 128, 128);
        else if (i < 65536) packOne(Wl2, Wr2, wp2, i - 49152, 128, 64);
        else packOne(Wc1, Wc1, wpc, i - 65536, 64, 32);
    }
    grid.sync();

    // ---- layer 0 ----
    agg_phase<6>((const unsigned*)xb, nbr, cnt, (unsigned*)aggb, wgl, nwave, lane);
    grid.sync();
    mfma_strips<64, 128, true>(aggb, xb, wp0, b0, h0b, wgl, nwave, lane);
    grid.sync();

    // ---- layer 1 ----
    agg_phase<7>((const unsigned*)h0b, nbr, cnt, (unsigned*)aggb, wgl, nwave, lane);
    grid.sync();
    mfma_strips<128, 128, true>(aggb, h0b, wp1, b1, h1b, wgl, nwave, lane);
    grid.sync();

    // ---- layer 2 ----
    agg_phase<7>((const unsigned*)h1b, nbr, cnt, (unsigned*)aggb, wgl, nwave, lane);
    grid.sync();
    cls_strips(aggb, h1b, wp2, wpc, b2, bc1, Wc2, bc2, out,
               Hs + wave * 1024, wgl, nwave, lane);
}

// ================= fallback kernels (multi-kernel, full grids) ===============
__global__ __launch_bounds__(256) void
k_prep(const int* __restrict__ src, const int* __restrict__ dst,
       int* __restrict__ cnt, int* __restrict__ nbr,
       const float* __restrict__ x, unsigned* __restrict__ xb,
       const float* Wl0, const float* Wr0, const float* Wl1, const float* Wr1,
       const float* Wl2, const float* Wr2, const float* Wc1,
       unsigned short* wp0, unsigned short* wp1, unsigned short* wp2,
       unsigned short* wpc) {
    const int b = blockIdx.x, t = threadIdx.x;
    if (b < 2500) {
        int e = b * 256 + t;
        if (e < NE) {
            int d = dst[e];
            int p = atomicAdd(&cnt[d], 1);
            if (p < CAP) nbr[d * CAP + p] = src[e];
        }
    } else if (b < 5625) {
        int i = (b - 2500) * 256 + t;
        if (i < NN * 16) {
            float4 v = ((const float4*)x)[i];
            ((uint2*)xb)[i] = make_uint2(pk2(v.x, v.y), pk2(v.z, v.w));
        }
    } else {
        int idx = (b - 5625) * 256 + t;
        if (idx < 16384) packOne(Wl0, Wr0, wp0, idx, 64, 128);
        else if (idx < 49152) packOne(Wl1, Wr1, wp1, idx - 16384, 128, 128);
        else if (idx < 65536) packOne(Wl2, Wr2, wp2, idx - 49152, 128, 64);
        else if (idx < 67584) packOne(Wc1, Wc1, wpc, idx - 65536, 64, 32);
    }
}

template <int LOGC>
__global__ __launch_bounds__(256) void
k_aggregate(const unsigned* __restrict__ xu, const int* __restrict__ nbr,
            const int* __restrict__ cnt, unsigned* __restrict__ aggu, int N) {
    const int wgl = (blockIdx.x * 256 + threadIdx.x) >> 6;
    if (wgl >= N) return;
    agg_phase<LOGC>(xu, nbr, cnt, aggu, wgl, 1 << 30, threadIdx.x & 63);
}

template <int CIN, int COUT, bool RELU>
__global__ __launch_bounds__(256) void
k_mfma(const unsigned short* __restrict__ Agg, const unsigned short* __restrict__ X,
       const unsigned short* __restrict__ Wpack, const float* __restrict__ bias,
       unsigned short* __restrict__ outp) {
    const int wstrip = blockIdx.x * 4 + (threadIdx.x >> 6);
    mfma_strips<CIN, COUT, RELU>(Agg, X, Wpack, bias, outp,
                                 wstrip, 1 << 30, threadIdx.x & 63);
}

__global__ __launch_bounds__(256) void
k_mfma_cls(const unsigned short* __restrict__ Agg, const unsigned short* __restrict__ X,
           const unsigned short* __restrict__ Wpack, const unsigned short* __restrict__ WpackC,
           const float* __restrict__ bias, const float* __restrict__ bc1,
           const float* __restrict__ Wc2, const float* __restrict__ bc2,
           float* __restrict__ out) {
    __shared__ __align__(16) short Hs[4 * 16 * 64];
    const int wave = threadIdx.x >> 6;
    const int wstrip = blockIdx.x * 4 + wave;
    cls_strips(Agg, X, Wpack, WpackC, bias, bc1, Wc2, bc2, out,
               Hs + wave * 1024, wstrip, 1 << 30, threadIdx.x & 63);
}

extern "C" void kernel_launch(void* const* d_in, const int* in_sizes, int n_in,
                              void* d_out, int out_size, void* d_ws, size_t ws_size,
                              hipStream_t stream) {
    const float* x   = (const float*)d_in[0];
    const int*   ei  = (const int*)d_in[1];   // [2, NE] int32
    const int*   src = ei;
    const int*   dst = ei + NE;
    const float* Wl0 = (const float*)d_in[2];
    const float* Wr0 = (const float*)d_in[3];
    const float* b0  = (const float*)d_in[4];
    const float* Wl1 = (const float*)d_in[5];
    const float* Wr1 = (const float*)d_in[6];
    const float* b1  = (const float*)d_in[7];
    const float* Wl2 = (const float*)d_in[8];
    const float* Wr2 = (const float*)d_in[9];
    const float* b2  = (const float*)d_in[10];
    const float* Wc1 = (const float*)d_in[11];
    const float* bc1 = (const float*)d_in[12];
    const float* Wc2 = (const float*)d_in[13];
    const float* bc2 = (const float*)d_in[14];
    float* out = (float*)d_out;

    char*  ws   = (char*)d_ws;
    int*   cnt  = (int*)(ws);
    unsigned short* wp0 = (unsigned short*)(ws + (size_t)256 * 1024);
    unsigned short* wp1 = (unsigned short*)(ws + (size_t)352 * 1024);
    unsigned short* wp2 = (unsigned short*)(ws + (size_t)448 * 1024);
    unsigned short* wpc = (unsigned short*)(ws + (size_t)512 * 1024);
    int*   nbr  = (int*)(ws + (size_t)1 * (1 << 20));
    unsigned short* xb   = (unsigned short*)(ws + (size_t)16 * (1 << 20));
    unsigned short* aggb = (unsigned short*)(ws + (size_t)24 * (1 << 20));
    unsigned short* h0b  = (unsigned short*)(ws + (size_t)40 * (1 << 20));
    unsigned short* h1b  = (unsigned short*)(ws + (size_t)56 * (1 << 20));

    hipMemsetAsync(cnt, 0, (size_t)NN * sizeof(int), stream);

    // ---- cooperative path: 512-thread blocks, grid <= 512 (no idle blocks) ----
    bool coop_ok = false;
    int maxBpc = 0, ncu = 0, dev = 0;
    hipGetDevice(&dev);
    hipDeviceGetAttribute(&ncu, hipDeviceAttributeMultiprocessorCount, dev);
    hipError_t qerr = hipOccupancyMaxActiveBlocksPerMultiprocessor(
        &maxBpc, (const void*)k_all, 512, 0);
    if (qerr == hipSuccess && maxBpc > 0 && ncu > 0) {
        int bpc = (maxBpc < 2) ? maxBpc : 2;
        int grid = bpc * ncu;
        if (grid > 512) grid = 512;
        const int* srcp = src; const int* dstp = dst;
        void* args[] = {
            (void*)&srcp, (void*)&dstp, (void*)&x,
            (void*)&Wl0, (void*)&Wr0, (void*)&b0,
            (void*)&Wl1, (void*)&Wr1, (void*)&b1,
            (void*)&Wl2, (void*)&Wr2, (void*)&b2,
            (void*)&Wc1, (void*)&bc1, (void*)&Wc2, (void*)&bc2,
            (void*)&cnt, (void*)&nbr, (void*)&xb,
            (void*)&wp0, (void*)&wp1, (void*)&wp2, (void*)&wpc,
            (void*)&aggb, (void*)&h0b, (void*)&h1b,
            (void*)&out
        };
        hipError_t lerr = hipLaunchCooperativeKernel((const void*)k_all, dim3(grid),
                                                     dim3(512), args, 0, stream);
        if (lerr == hipSuccess) coop_ok = true;
        else (void)hipGetLastError();
    } else {
        (void)hipGetLastError();
    }

    // ---- fallback: proven multi-kernel pipeline ----
    if (!coop_ok) {
        const int B = 256;
        const int AGG_GRID = (NN + 3) / 4;
        const int STRIP_GRID = (NSTRIP + 3) / 4;   // 782

        k_prep<<<5889, B, 0, stream>>>(src, dst, cnt, nbr, x, (unsigned*)xb,
                                       Wl0, Wr0, Wl1, Wr1, Wl2, Wr2, Wc1,
                                       wp0, wp1, wp2, wpc);

        k_aggregate<6><<<AGG_GRID, B, 0, stream>>>((const unsigned*)xb, nbr, cnt,
                                                   (unsigned*)aggb, NN);
        k_mfma<64, 128, true><<<STRIP_GRID, B, 0, stream>>>(aggb, xb, wp0, b0, h0b);

        k_aggregate<7><<<AGG_GRID, B, 0, stream>>>((const unsigned*)h0b, nbr, cnt,
                                                   (unsigned*)aggb, NN);
        k_mfma<128, 128, true><<<STRIP_GRID, B, 0, stream>>>(aggb, h0b, wp1, b1, h1b);

        k_aggregate<7><<<AGG_GRID, B, 0, stream>>>((const unsigned*)h1b, nbr, cnt,
                                                   (unsigned*)aggb, NN);
        k_mfma_cls<<<STRIP_GRID, B, 0, stream>>>(aggb, h1b, wp2, wpc, b2, bc1, Wc2, bc2,
                                                 out);
    }
}

// Round 18
// 243.836 us; speedup vs baseline: 3.2629x; 2.5672x over previous
//
#include <hip/hip_runtime.h>
#include <math.h>

#define NN 50000
#define NE 640000
#define CAP 64                    // slot capacity; Poisson(12.8) max deg ~40 << 64
#define NSTRIP (NN / 16)          // 3125 16-row strips (50000 = 3125*16 exactly)

typedef short short8 __attribute__((ext_vector_type(8)));   // 8 bf16 (4 VGPRs)
typedef float f32x4  __attribute__((ext_vector_type(4)));   // MFMA accumulator

// ---- bf16 helpers (RNE pack, cheap unpack) ----------------------------------
__device__ __forceinline__ unsigned bfr(float f) {
    unsigned u = __float_as_uint(f);
    return (u + 0x7FFFu + ((u >> 16) & 1u)) >> 16;
}
__device__ __forceinline__ unsigned pk2(float a, float b) { return bfr(a) | (bfr(b) << 16); }
__device__ __forceinline__ float bflo(unsigned u) { return __uint_as_float(u << 16); }
__device__ __forceinline__ float bfhi(unsigned u) { return __uint_as_float(u & 0xFFFF0000u); }

// ---- weight pack into MFMA B-frag layout (bf16) -----------------------------
__device__ __forceinline__ void packOne(const float* Wl, const float* Wr,
                                        unsigned short* wp, int idx,
                                        int CIN, int COUT) {
    int k = idx / COUT, n = idx % COUT;
    float v = (k < CIN) ? Wl[k * COUT + n] : Wr[(k - CIN) * COUT + n];
    int kt = k >> 5, quad = (k >> 3) & 3, j = k & 7;
    int nt = n >> 4, l16 = n & 15;
    int NT = COUT / 16;
    wp[(((kt * NT + nt) * 64) + quad * 16 + l16) * 8 + j] = (unsigned short)bfr(v);
}

// ---- fused prep: bucket-CSR fill + x->bf16 + all weight packs ---------------
__global__ __launch_bounds__(256) void
k_prep(const int* __restrict__ src, const int* __restrict__ dst,
       int* __restrict__ cnt, int* __restrict__ nbr,
       const float* __restrict__ x, unsigned* __restrict__ xb,
       const float* Wl0, const float* Wr0, const float* Wl1, const float* Wr1,
       const float* Wl2, const float* Wr2, const float* Wc1,
       unsigned short* wp0, unsigned short* wp1, unsigned short* wp2,
       unsigned short* wpc) {
    const int b = blockIdx.x, t = threadIdx.x;
    if (b < 2500) {
        int e = b * 256 + t;
        if (e < NE) {
            int d = dst[e];
            int p = atomicAdd(&cnt[d], 1);
            if (p < CAP) nbr[d * CAP + p] = src[e];
        }
    } else if (b < 5625) {
        int i = (b - 2500) * 256 + t;          // NN*16 = 800000 float4 groups
        if (i < NN * 16) {
            float4 v = ((const float4*)x)[i];
            ((uint2*)xb)[i] = make_uint2(pk2(v.x, v.y), pk2(v.z, v.w));
        }
    } else {
        int idx = (b - 5625) * 256 + t;
        if (idx < 16384) packOne(Wl0, Wr0, wp0, idx, 64, 128);
        else if (idx < 49152) packOne(Wl1, Wr1, wp1, idx - 16384, 128, 128);
        else if (idx < 65536) packOne(Wl2, Wr2, wp2, idx - 49152, 128, 64);
        else if (idx < 67584) packOne(Wc1, Wc1, wpc, idx - 65536, 64, 32);
    }
}

// ---- per-wave gather of 16 nodes into wave-private LDS ----------------------
// Quarter-wave per neighbor (R11-verified), slot prefetch one node ahead.
// aw row stride RP = CIN+8 shorts -> 2-way bank aliasing on all LDS ops (free).
template <int CIN, int RP>
__device__ __forceinline__ void
gather16(short* __restrict__ aw, const unsigned* __restrict__ xu,
         const int* __restrict__ nbr, const int* __restrict__ cnt,
         int row_base, int lane, int qw, int l16) {
    constexpr int RU = CIN / 2;    // uints per row
    constexpr int PC = CIN / 32;   // uints per lane16 per row: 2 | 4

    int dcur = cnt[row_base];
    int scur = nbr[row_base * CAP + lane];

    for (int it = 0; it < 16; ++it) {
        const int deg = dcur;
        const int sl  = scur;
        if (it + 1 < 16) {
            dcur = cnt[row_base + it + 1];
            scur = nbr[(row_base + it + 1) * CAP + lane];
        }
        const int m = (deg < CAP) ? deg : CAP;
        const int sc = (lane < m) ? sl : 0;

        float a[2 * PC] = {};
#pragma unroll 4
        for (int j = 0; j < m; j += 4) {
            const int n = __shfl(sc, (j + qw) & 63);
            const bool valid = (j + qw) < m;
            if (PC == 2) {
                const uint2 u = *(const uint2*)(xu + (size_t)n * RU + l16 * 2);
                if (valid) {
                    a[0] += bflo(u.x); a[1] += bfhi(u.x);
                    a[2] += bflo(u.y); a[3] += bfhi(u.y);
                }
            } else {
                const uint4 u = *(const uint4*)(xu + (size_t)n * RU + l16 * 4);
                if (valid) {
                    a[0] += bflo(u.x); a[1] += bfhi(u.x);
                    a[2] += bflo(u.y); a[3] += bfhi(u.y);
                    a[4] += bflo(u.z); a[5] += bfhi(u.z);
                    a[6] += bflo(u.w); a[7] += bfhi(u.w);
                }
            }
        }

#pragma unroll
        for (int c = 0; c < 2 * PC; ++c) {
            a[c] += __shfl_xor(a[c], 16);
            a[c] += __shfl_xor(a[c], 32);
        }

        if (qw == 0) {
            const float di = 1.0f / (float)((deg > 1) ? deg : 1);
            if (PC == 2) {
                uint2 o = make_uint2(pk2(a[0] * di, a[1] * di), pk2(a[2] * di, a[3] * di));
                *(uint2*)&aw[it * RP + l16 * 4] = o;
            } else {
                uint4 o = make_uint4(pk2(a[0] * di, a[1] * di), pk2(a[2] * di, a[3] * di),
                                     pk2(a[4] * di, a[5] * di), pk2(a[6] * di, a[7] * di));
                *(uint4*)&aw[it * RP + l16 * 8] = o;
            }
        }
    }
}

// ---- fused SAGE layer: wave-private gather -> MFMA strip, NO barriers -------
// out = act( [agg|x] @ [Wl;Wr] + b ). agg A-frags from wave-private LDS,
// x A-frags direct from global, B-frags from L2-hot packed table.
template <int CIN, int COUT, bool RELU>
__global__ __launch_bounds__(256) void
k_layer(const unsigned short* __restrict__ Xprev, const int* __restrict__ nbr,
        const int* __restrict__ cnt, const unsigned short* __restrict__ Wpack,
        const float* __restrict__ bias, unsigned short* __restrict__ outp) {
    constexpr int KT = (2 * CIN) / 32;
    constexpr int NT = COUT / 16;
    constexpr int RP = CIN + 8;       // LDS row stride (shorts)

    __shared__ __align__(16) short As[4 * 16 * RP];

    const int t = threadIdx.x, wave = t >> 6, lane = t & 63;
    const int qw = lane >> 4, l16 = lane & 15;
    const int strip = blockIdx.x * 4 + wave;
    if (strip >= NSTRIP) return;      // tail waves of last block (no barriers used)
    const int row_base = strip * 16;

    short* aw = As + wave * 16 * RP;

    gather16<CIN, RP>(aw, (const unsigned*)Xprev, nbr, cnt, row_base, lane, qw, l16);

    f32x4 acc[NT] = {};

    for (int kt = 0; kt < KT; ++kt) {
        short8 a0;
        if (kt < KT / 2) {
            a0 = *(const short8*)&aw[l16 * RP + kt * 32 + qw * 8];
        } else {
            const int kb = kt * 32 - CIN;
            a0 = *(const short8*)(Xprev + (size_t)(row_base + l16) * CIN + kb + qw * 8);
        }
#pragma unroll
        for (int nt = 0; nt < NT; ++nt) {
            const short8 bfrag = *(const short8*)(Wpack + (size_t)((kt * NT + nt) * 64 + lane) * 8);
            acc[nt] = __builtin_amdgcn_mfma_f32_16x16x32_bf16(a0, bfrag, acc[nt], 0, 0, 0);
        }
    }

#pragma unroll
    for (int nt = 0; nt < NT; ++nt) {
        const int col = nt * 16 + l16;
        const float bb = bias[col];
#pragma unroll
        for (int rg = 0; rg < 4; ++rg) {
            const int row = row_base + qw * 4 + rg;
            float v = acc[nt][rg] + bb;
            if (RELU) v = fmaxf(v, 0.f);
            outp[(size_t)row * COUT + col] = (unsigned short)bfr(v);
        }
    }
}

// ---- fused layer 2 + classifier (same structure, wave-private throughout) ---
__global__ __launch_bounds__(256) void
k_layer_cls(const unsigned short* __restrict__ Xprev, const int* __restrict__ nbr,
            const int* __restrict__ cnt, const unsigned short* __restrict__ Wpack,
            const unsigned short* __restrict__ WpackC, const float* __restrict__ bias,
            const float* __restrict__ bc1, const float* __restrict__ Wc2,
            const float* __restrict__ bc2, float* __restrict__ out) {
    constexpr int CIN = 128, NT = 4, KT = 8;
    constexpr int RP = CIN + 8;
    constexpr int HP = 72;            // h row stride (64+8) -> 2-way banks

    __shared__ __align__(16) short As[4 * 16 * RP];   // 17.4 KB
    __shared__ __align__(16) short Hs[4 * 16 * HP];   //  9.2 KB

    const int t = threadIdx.x, wave = t >> 6, lane = t & 63;
    const int qw = lane >> 4, l16 = lane & 15;
    const int strip = blockIdx.x * 4 + wave;
    if (strip >= NSTRIP) return;
    const int row_base = strip * 16;

    short* aw = As + wave * 16 * RP;
    short* hw = Hs + wave * 16 * HP;

    gather16<CIN, RP>(aw, (const unsigned*)Xprev, nbr, cnt, row_base, lane, qw, l16);

    f32x4 acc[NT] = {};

    for (int kt = 0; kt < KT; ++kt) {
        short8 a0;
        if (kt < KT / 2) {
            a0 = *(const short8*)&aw[l16 * RP + kt * 32 + qw * 8];
        } else {
            const int kb = kt * 32 - CIN;
            a0 = *(const short8*)(Xprev + (size_t)(row_base + l16) * CIN + kb + qw * 8);
        }
#pragma unroll
        for (int nt = 0; nt < NT; ++nt) {
            const short8 bfrag = *(const short8*)(Wpack + (size_t)((kt * NT + nt) * 64 + lane) * 8);
            acc[nt] = __builtin_amdgcn_mfma_f32_16x16x32_bf16(a0, bfrag, acc[nt], 0, 0, 0);
        }
    }

    // h strip (C-layout) -> wave-private LDS (row-major, stride HP): +b2
#pragma unroll
    for (int nt = 0; nt < NT; ++nt) {
        const float bb = bias[nt * 16 + l16];
#pragma unroll
        for (int rg = 0; rg < 4; ++rg)
            hw[(qw * 4 + rg) * HP + nt * 16 + l16] =
                (unsigned short)bfr(acc[nt][rg] + bb);
    }

    // classifier GEMM: h(16x64) @ Wc1(64x32); A-frag: m=l16, k=quad*8+j
    f32x4 sacc[2] = {};
#pragma unroll
    for (int kt2 = 0; kt2 < 2; ++kt2) {
        const short8 af = *(const short8*)&hw[l16 * HP + kt2 * 32 + qw * 8];
#pragma unroll
        for (int nt2 = 0; nt2 < 2; ++nt2) {
            const short8 bf = *(const short8*)(WpackC + (size_t)((kt2 * 2 + nt2) * 64 + lane) * 8);
            sacc[nt2] = __builtin_amdgcn_mfma_f32_16x16x32_bf16(af, bf, sacc[nt2], 0, 0, 0);
        }
    }

    // +bc1, ReLU, dot Wc2, reduce over 16 cols, +bc2, sigmoid
    const float b1a = bc1[l16], b1b = bc1[16 + l16];
    const float w2a = Wc2[l16], w2b = Wc2[16 + l16];
    const float b2v = bc2[0];
#pragma unroll
    for (int rg = 0; rg < 4; ++rg) {
        float p = fmaxf(sacc[0][rg] + b1a, 0.f) * w2a +
                  fmaxf(sacc[1][rg] + b1b, 0.f) * w2b;
#pragma unroll
        for (int off = 1; off < 16; off <<= 1) p += __shfl_xor(p, off);
        if (l16 == 0) {
            const int row = row_base + qw * 4 + rg;
            out[row] = 1.0f / (1.0f + expf(-(p + b2v)));
        }
    }
}

extern "C" void kernel_launch(void* const* d_in, const int* in_sizes, int n_in,
                              void* d_out, int out_size, void* d_ws, size_t ws_size,
                              hipStream_t stream) {
    const float* x   = (const float*)d_in[0];
    const int*   ei  = (const int*)d_in[1];   // [2, NE] int32
    const int*   src = ei;
    const int*   dst = ei + NE;
    const float* Wl0 = (const float*)d_in[2];
    const float* Wr0 = (const float*)d_in[3];
    const float* b0  = (const float*)d_in[4];
    const float* Wl1 = (const float*)d_in[5];
    const float* Wr1 = (const float*)d_in[6];
    const float* b1  = (const float*)d_in[7];
    const float* Wl2 = (const float*)d_in[8];
    const float* Wr2 = (const float*)d_in[9];
    const float* b2  = (const float*)d_in[10];
    const float* Wc1 = (const float*)d_in[11];
    const float* bc1 = (const float*)d_in[12];
    const float* Wc2 = (const float*)d_in[13];
    const float* bc2 = (const float*)d_in[14];
    float* out = (float*)d_out;

    // workspace layout (bytes):
    //   [0,200K)   cnt  (NN ints)
    //   [256K)     wp0 32K | [352K) wp1 64K | [448K) wp2 32K | [512K) wpc 4K
    //   [1M)       nbr  NN*CAP ints (12.8M)
    //   [16M)      xb   NN*64  bf16 ( 6.4M)
    //   [24M)      h0b  NN*128 bf16 (12.8M)
    //   [40M)      h1b  NN*128 bf16 (12.8M)
    char*  ws   = (char*)d_ws;
    int*   cnt  = (int*)(ws);
    unsigned short* wp0 = (unsigned short*)(ws + (size_t)256 * 1024);
    unsigned short* wp1 = (unsigned short*)(ws + (size_t)352 * 1024);
    unsigned short* wp2 = (unsigned short*)(ws + (size_t)448 * 1024);
    unsigned short* wpc = (unsigned short*)(ws + (size_t)512 * 1024);
    int*   nbr  = (int*)(ws + (size_t)1 * (1 << 20));
    unsigned short* xb  = (unsigned short*)(ws + (size_t)16 * (1 << 20));
    unsigned short* h0b = (unsigned short*)(ws + (size_t)24 * (1 << 20));
    unsigned short* h1b = (unsigned short*)(ws + (size_t)40 * (1 << 20));

    const int B = 256;
    const int LAYER_GRID = (NSTRIP + 3) / 4;   // 782 blocks, 1 strip per wave

    // ---- prep: CSR fill + conversions (2 dispatches) ----
    hipMemsetAsync(cnt, 0, (size_t)NN * sizeof(int), stream);
    k_prep<<<5889, B, 0, stream>>>(src, dst, cnt, nbr, x, (unsigned*)xb,
                                   Wl0, Wr0, Wl1, Wr1, Wl2, Wr2, Wc1,
                                   wp0, wp1, wp2, wpc);

    // ---- 3 fused layers (barrier-free per-wave gather + MFMA) ----
    k_layer<64, 128, true><<<LAYER_GRID, B, 0, stream>>>(xb, nbr, cnt, wp0, b0, h0b);
    k_layer<128, 128, true><<<LAYER_GRID, B, 0, stream>>>(h0b, nbr, cnt, wp1, b1, h1b);
    k_layer_cls<<<LAYER_GRID, B, 0, stream>>>(h1b, nbr, cnt, wp2, wpc, b2, bc1, Wc2, bc2,
                                              out);
}

// Round 19
// 241.631 us; speedup vs baseline: 3.2927x; 1.0091x over previous
//
#include <hip/hip_runtime.h>
#include <math.h>

#define NN 50000
#define NE 640000
#define CAP 64                    // slot capacity; Poisson(12.8) max deg ~40 << 64
#define NSTRIP (NN / 16)          // 3125 16-row strips (50000 = 3125*16 exactly)

typedef short short8 __attribute__((ext_vector_type(8)));   // 8 bf16 (4 VGPRs)
typedef float f32x4  __attribute__((ext_vector_type(4)));   // MFMA accumulator

// ---- bf16 helpers (RNE pack, cheap unpack) ----------------------------------
__device__ __forceinline__ unsigned bfr(float f) {
    unsigned u = __float_as_uint(f);
    return (u + 0x7FFFu + ((u >> 16) & 1u)) >> 16;
}
__device__ __forceinline__ unsigned pk2(float a, float b) { return bfr(a) | (bfr(b) << 16); }
__device__ __forceinline__ float bflo(unsigned u) { return __uint_as_float(u << 16); }
__device__ __forceinline__ float bfhi(unsigned u) { return __uint_as_float(u & 0xFFFF0000u); }

// ---- weight pack into MFMA B-frag layout (bf16) -----------------------------
__device__ __forceinline__ void packOne(const float* Wl, const float* Wr,
                                        unsigned short* wp, int idx,
                                        int CIN, int COUT) {
    int k = idx / COUT, n = idx % COUT;
    float v = (k < CIN) ? Wl[k * COUT + n] : Wr[(k - CIN) * COUT + n];
    int kt = k >> 5, quad = (k >> 3) & 3, j = k & 7;
    int nt = n >> 4, l16 = n & 15;
    int NT = COUT / 16;
    wp[(((kt * NT + nt) * 64) + quad * 16 + l16) * 8 + j] = (unsigned short)bfr(v);
}

// ---- fused prep: bucket-CSR fill + x->bf16 + all weight packs ---------------
__global__ __launch_bounds__(256) void
k_prep(const int* __restrict__ src, const int* __restrict__ dst,
       int* __restrict__ cnt, int* __restrict__ nbr,
       const float* __restrict__ x, unsigned* __restrict__ xb,
       const float* Wl0, const float* Wr0, const float* Wl1, const float* Wr1,
       const float* Wl2, const float* Wr2, const float* Wc1,
       unsigned short* wp0, unsigned short* wp1, unsigned short* wp2,
       unsigned short* wpc) {
    const int b = blockIdx.x, t = threadIdx.x;
    if (b < 2500) {
        int e = b * 256 + t;
        if (e < NE) {
            int d = dst[e];
            int p = atomicAdd(&cnt[d], 1);
            if (p < CAP) nbr[d * CAP + p] = src[e];
        }
    } else if (b < 5625) {
        int i = (b - 2500) * 256 + t;          // NN*16 = 800000 float4 groups
        if (i < NN * 16) {
            float4 v = ((const float4*)x)[i];
            ((uint2*)xb)[i] = make_uint2(pk2(v.x, v.y), pk2(v.z, v.w));
        }
    } else {
        int idx = (b - 5625) * 256 + t;
        if (idx < 16384) packOne(Wl0, Wr0, wp0, idx, 64, 128);
        else if (idx < 49152) packOne(Wl1, Wr1, wp1, idx - 16384, 128, 128);
        else if (idx < 65536) packOne(Wl2, Wr2, wp2, idx - 49152, 128, 64);
        else if (idx < 67584) packOne(Wc1, Wc1, wpc, idx - 65536, 64, 32);
    }
}

// ---- per-wave gather of 8 nodes into the strip's shared LDS tile ------------
// Quarter-wave per neighbor (R11-verified), slot prefetch one node ahead.
template <int CIN, int RP>
__device__ __forceinline__ void
gather8(short* __restrict__ aw, const unsigned* __restrict__ xu,
        const int* __restrict__ nbr, const int* __restrict__ cnt,
        int node0, int lds_row0, int lane, int qw, int l16) {
    constexpr int RU = CIN / 2;    // uints per row
    constexpr int PC = CIN / 32;   // uints per lane16 per row: 2 | 4

    int dcur = cnt[node0];
    int scur = nbr[node0 * CAP + lane];

    for (int it = 0; it < 8; ++it) {
        const int deg = dcur;
        const int sl  = scur;
        if (it + 1 < 8) {
            dcur = cnt[node0 + it + 1];
            scur = nbr[(node0 + it + 1) * CAP + lane];
        }
        const int m = (deg < CAP) ? deg : CAP;
        const int sc = (lane < m) ? sl : 0;

        float a[2 * PC] = {};
#pragma unroll 4
        for (int j = 0; j < m; j += 4) {
            const int n = __shfl(sc, (j + qw) & 63);
            const bool valid = (j + qw) < m;
            if (PC == 2) {
                const uint2 u = *(const uint2*)(xu + (size_t)n * RU + l16 * 2);
                if (valid) {
                    a[0] += bflo(u.x); a[1] += bfhi(u.x);
                    a[2] += bflo(u.y); a[3] += bfhi(u.y);
                }
            } else {
                const uint4 u = *(const uint4*)(xu + (size_t)n * RU + l16 * 4);
                if (valid) {
                    a[0] += bflo(u.x); a[1] += bfhi(u.x);
                    a[2] += bflo(u.y); a[3] += bfhi(u.y);
                    a[4] += bflo(u.z); a[5] += bfhi(u.z);
                    a[6] += bflo(u.w); a[7] += bfhi(u.w);
                }
            }
        }

#pragma unroll
        for (int c = 0; c < 2 * PC; ++c) {
            a[c] += __shfl_xor(a[c], 16);
            a[c] += __shfl_xor(a[c], 32);
        }

        if (qw == 0) {
            const float di = 1.0f / (float)((deg > 1) ? deg : 1);
            const int r = lds_row0 + it;
            if (PC == 2) {
                uint2 o = make_uint2(pk2(a[0] * di, a[1] * di), pk2(a[2] * di, a[3] * di));
                *(uint2*)&aw[r * RP + l16 * 4] = o;
            } else {
                uint4 o = make_uint4(pk2(a[0] * di, a[1] * di), pk2(a[2] * di, a[3] * di),
                                     pk2(a[4] * di, a[5] * di), pk2(a[6] * di, a[7] * di));
                *(uint4*)&aw[r * RP + l16 * 8] = o;
            }
        }
    }
}

// ---- fused SAGE layer: 2 waves per strip (8-row gather each), one barrier ---
// 512 threads = 8 waves = 4 strips/block. MFMA split by column halves.
template <int CIN, int COUT, bool RELU>
__global__ __launch_bounds__(512) void
k_layer(const unsigned short* __restrict__ Xprev, const int* __restrict__ nbr,
        const int* __restrict__ cnt, const unsigned short* __restrict__ Wpack,
        const float* __restrict__ bias, unsigned short* __restrict__ outp) {
    constexpr int KT  = (2 * CIN) / 32;
    constexpr int NT  = COUT / 16;
    constexpr int NTH = NT / 2;        // nt tiles per wave
    constexpr int RP  = CIN + 8;       // LDS row stride (shorts)

    __shared__ __align__(16) short As[4 * 16 * RP];

    const int t = threadIdx.x, wave = t >> 6, lane = t & 63;
    const int qw = lane >> 4, l16 = lane & 15;
    const int sl = wave >> 1;          // strip-local 0..3
    const int hf = wave & 1;           // half 0|1
    int strip = blockIdx.x * 4 + sl;
    if (strip >= NSTRIP) strip = NSTRIP - 1;   // clamp: uniform barriers, dup writes identical
    const int row_base = strip * 16;

    short* aw = As + sl * 16 * RP;

    gather8<CIN, RP>(aw, (const unsigned*)Xprev, nbr, cnt,
                     row_base + hf * 8, hf * 8, lane, qw, l16);
    __syncthreads();

    f32x4 acc[NTH] = {};

    for (int kt = 0; kt < KT; ++kt) {
        short8 a0;
        if (kt < KT / 2) {
            a0 = *(const short8*)&aw[l16 * RP + kt * 32 + qw * 8];
        } else {
            const int kb = kt * 32 - CIN;
            a0 = *(const short8*)(Xprev + (size_t)(row_base + l16) * CIN + kb + qw * 8);
        }
#pragma unroll
        for (int ntl = 0; ntl < NTH; ++ntl) {
            const int nt = hf * NTH + ntl;
            const short8 bfrag = *(const short8*)(Wpack + (size_t)((kt * NT + nt) * 64 + lane) * 8);
            acc[ntl] = __builtin_amdgcn_mfma_f32_16x16x32_bf16(a0, bfrag, acc[ntl], 0, 0, 0);
        }
    }

#pragma unroll
    for (int ntl = 0; ntl < NTH; ++ntl) {
        const int col = (hf * NTH + ntl) * 16 + l16;
        const float bb = bias[col];
#pragma unroll
        for (int rg = 0; rg < 4; ++rg) {
            const int row = row_base + qw * 4 + rg;
            float v = acc[ntl][rg] + bb;
            if (RELU) v = fmaxf(v, 0.f);
            outp[(size_t)row * COUT + col] = (unsigned short)bfr(v);
        }
    }
}

// ---- fused layer 2 + classifier (2 waves per strip) -------------------------
__global__ __launch_bounds__(512) void
k_layer_cls(const unsigned short* __restrict__ Xprev, const int* __restrict__ nbr,
            const int* __restrict__ cnt, const unsigned short* __restrict__ Wpack,
            const unsigned short* __restrict__ WpackC, const float* __restrict__ bias,
            const float* __restrict__ bc1, const float* __restrict__ Wc2,
            const float* __restrict__ bc2, float* __restrict__ out) {
    constexpr int CIN = 128, NT = 4, KT = 8, NTH = 2;
    constexpr int RP = CIN + 8;
    constexpr int HP = 72;            // h row stride (64+8)

    __shared__ __align__(16) short As[4 * 16 * RP];   // 17.4 KB
    __shared__ __align__(16) short Hs[4 * 16 * HP];   //  9.2 KB

    const int t = threadIdx.x, wave = t >> 6, lane = t & 63;
    const int qw = lane >> 4, l16 = lane & 15;
    const int sl = wave >> 1;
    const int hf = wave & 1;
    int strip = blockIdx.x * 4 + sl;
    if (strip >= NSTRIP) strip = NSTRIP - 1;
    const int row_base = strip * 16;

    short* aw = As + sl * 16 * RP;
    short* hw = Hs + sl * 16 * HP;

    gather8<CIN, RP>(aw, (const unsigned*)Xprev, nbr, cnt,
                     row_base + hf * 8, hf * 8, lane, qw, l16);
    __syncthreads();

    f32x4 acc[NTH] = {};

    for (int kt = 0; kt < KT; ++kt) {
        short8 a0;
        if (kt < KT / 2) {
            a0 = *(const short8*)&aw[l16 * RP + kt * 32 + qw * 8];
        } else {
            const int kb = kt * 32 - CIN;
            a0 = *(const short8*)(Xprev + (size_t)(row_base + l16) * CIN + kb + qw * 8);
        }
#pragma unroll
        for (int ntl = 0; ntl < NTH; ++ntl) {
            const int nt = hf * NTH + ntl;
            const short8 bfrag = *(const short8*)(Wpack + (size_t)((kt * NT + nt) * 64 + lane) * 8);
            acc[ntl] = __builtin_amdgcn_mfma_f32_16x16x32_bf16(a0, bfrag, acc[ntl], 0, 0, 0);
        }
    }

    // h strip (C-layout) -> shared strip LDS: +b2, no relu; wave hf covers its 32 cols
#pragma unroll
    for (int ntl = 0; ntl < NTH; ++ntl) {
        const int col = (hf * NTH + ntl) * 16 + l16;
        const float bb = bias[col];
#pragma unroll
        for (int rg = 0; rg < 4; ++rg)
            hw[(qw * 4 + rg) * HP + col] = (unsigned short)bfr(acc[ntl][rg] + bb);
    }
    __syncthreads();

    // classifier on wave hf==0 only (tiny): h(16x64) @ Wc1(64x32)
    if (hf == 0) {
        f32x4 sacc[2] = {};
#pragma unroll
        for (int kt2 = 0; kt2 < 2; ++kt2) {
            const short8 af = *(const short8*)&hw[l16 * HP + kt2 * 32 + qw * 8];
#pragma unroll
            for (int nt2 = 0; nt2 < 2; ++nt2) {
                const short8 bf = *(const short8*)(WpackC + (size_t)((kt2 * 2 + nt2) * 64 + lane) * 8);
                sacc[nt2] = __builtin_amdgcn_mfma_f32_16x16x32_bf16(af, bf, sacc[nt2], 0, 0, 0);
            }
        }

        const float b1a = bc1[l16], b1b = bc1[16 + l16];
        const float w2a = Wc2[l16], w2b = Wc2[16 + l16];
        const float b2v = bc2[0];
#pragma unroll
        for (int rg = 0; rg < 4; ++rg) {
            float p = fmaxf(sacc[0][rg] + b1a, 0.f) * w2a +
                      fmaxf(sacc[1][rg] + b1b, 0.f) * w2b;
#pragma unroll
            for (int off = 1; off < 16; off <<= 1) p += __shfl_xor(p, off);
            if (l16 == 0) {
                const int row = row_base + qw * 4 + rg;
                out[row] = 1.0f / (1.0f + expf(-(p + b2v)));
            }
        }
    }
}

extern "C" void kernel_launch(void* const* d_in, const int* in_sizes, int n_in,
                              void* d_out, int out_size, void* d_ws, size_t ws_size,
                              hipStream_t stream) {
    const float* x   = (const float*)d_in[0];
    const int*   ei  = (const int*)d_in[1];   // [2, NE] int32
    const int*   src = ei;
    const int*   dst = ei + NE;
    const float* Wl0 = (const float*)d_in[2];
    const float* Wr0 = (const float*)d_in[3];
    const float* b0  = (const float*)d_in[4];
    const float* Wl1 = (const float*)d_in[5];
    const float* Wr1 = (const float*)d_in[6];
    const float* b1  = (const float*)d_in[7];
    const float* Wl2 = (const float*)d_in[8];
    const float* Wr2 = (const float*)d_in[9];
    const float* b2  = (const float*)d_in[10];
    const float* Wc1 = (const float*)d_in[11];
    const float* bc1 = (const float*)d_in[12];
    const float* Wc2 = (const float*)d_in[13];
    const float* bc2 = (const float*)d_in[14];
    float* out = (float*)d_out;

    // workspace layout (bytes):
    //   [0,200K)   cnt  (NN ints)
    //   [256K)     wp0 32K | [352K) wp1 64K | [448K) wp2 32K | [512K) wpc 4K
    //   [1M)       nbr  NN*CAP ints (12.8M)
    //   [16M)      xb   NN*64  bf16 ( 6.4M)
    //   [24M)      h0b  NN*128 bf16 (12.8M)
    //   [40M)      h1b  NN*128 bf16 (12.8M)
    char*  ws   = (char*)d_ws;
    int*   cnt  = (int*)(ws);
    unsigned short* wp0 = (unsigned short*)(ws + (size_t)256 * 1024);
    unsigned short* wp1 = (unsigned short*)(ws + (size_t)352 * 1024);
    unsigned short* wp2 = (unsigned short*)(ws + (size_t)448 * 1024);
    unsigned short* wpc = (unsigned short*)(ws + (size_t)512 * 1024);
    int*   nbr  = (int*)(ws + (size_t)1 * (1 << 20));
    unsigned short* xb  = (unsigned short*)(ws + (size_t)16 * (1 << 20));
    unsigned short* h0b = (unsigned short*)(ws + (size_t)24 * (1 << 20));
    unsigned short* h1b = (unsigned short*)(ws + (size_t)40 * (1 << 20));

    const int LAYER_GRID = (NSTRIP + 3) / 4;   // 782 blocks x 512 thr, 2 waves/strip

    // ---- prep: CSR fill + conversions ----
    hipMemsetAsync(cnt, 0, (size_t)NN * sizeof(int), stream);
    k_prep<<<5889, 256, 0, stream>>>(src, dst, cnt, nbr, x, (unsigned*)xb,
                                     Wl0, Wr0, Wl1, Wr1, Wl2, Wr2, Wc1,
                                     wp0, wp1, wp2, wpc);

    // ---- 3 fused layers (per-strip gather + MFMA, 2 waves/strip) ----
    k_layer<64, 128, true><<<LAYER_GRID, 512, 0, stream>>>(xb, nbr, cnt, wp0, b0, h0b);
    k_layer<128, 128, true><<<LAYER_GRID, 512, 0, stream>>>(h0b, nbr, cnt, wp1, b1, h1b);
    k_layer_cls<<<LAYER_GRID, 512, 0, stream>>>(h1b, nbr, cnt, wp2, wpc, b2, bc1, Wc2, bc2,
                                                out);
}